// Round 3
// baseline (2829.273 us; speedup 1.0000x reference)
//
#include <hip/hip_runtime.h>
#include <stdint.h>

typedef unsigned int   uint32;
typedef unsigned short ushortT;

#define F_IN   256
#define NH1    128
#define NH2    64
#define NH3    32
#define NOUT   2
#define T_REAL 100
#define WT     16
#define NWIN   7
#define NS     4

// ---- workspace float offsets (total ~43.3K floats = 173 KB) ----
#define W1T_OFF 0        // [256][128]
#define W2T_OFF 32768    // [128][64]
#define W3T_OFF 40960    // [64][32]
#define WOT_OFF 43008    // [32][2]
#define B1_OFF  43072
#define B2_OFF  43200
#define B3_OFF  43264
#define BO_OFF  43296

// ---- LDS byte offsets (regions hand-aliased; peak 53248 B) ----
#define XS_OFF  0        // [64][72] f32 = 18432   (GEMM1 x-chunk)
#define U1_OFF  0        // [512][17] f32 = 34816
#define S1_OFF  34816    // [128] rows x 144 B (64 bf16 + pad) = 18432 -> ends 53248
#define U2_OFF  0        // [256][17] f32 = 17408
#define S2_OFF  17408    // [64] rows x 144 B = 9216  -> ends 26624
#define U3_OFF  26624    // [128][17] f32 = 8704  -> ends 35328 (s1T dead by then)
#define S3_OFF  0        // [32] rows x 144 B = 4608
#define UO_OFF  4608     // [8][17] f32 = 544
#define LDS_BYTES 53248

// fold BN scales into transposed weights
__global__ void prep_w(const float* __restrict__ W1, const float* __restrict__ W2,
                       const float* __restrict__ W3, const float* __restrict__ Wo,
                       const float* __restrict__ bn0g, const float* __restrict__ bn0v,
                       const float* __restrict__ bn1g, const float* __restrict__ bn1v,
                       const float* __restrict__ bn2g, const float* __restrict__ bn2v,
                       const float* __restrict__ bn3g, const float* __restrict__ bn3v,
                       float* __restrict__ ws)
{
    int idx = blockIdx.x * 256 + threadIdx.x;
    if (idx < 32768) {                       // W1T[k][h] = W1[h][k]*A[k]*G1[h]
        int k = idx >> 7, h = idx & 127;
        float A = bn0g[k] / sqrtf(bn0v[k] + 1e-5f);
        float G = bn1g[h] / sqrtf(bn1v[h] + 1e-5f);
        ws[W1T_OFF + idx] = W1[h * 256 + k] * A * G;
    } else if (idx < 40960) {                // W2T[k][h] = W2[h][k]*G2[h]
        int r = idx - 32768; int k = r >> 6, h = r & 63;
        float G = bn2g[h] / sqrtf(bn2v[h] + 1e-5f);
        ws[W2T_OFF + r] = W2[h * 128 + k] * G;
    } else if (idx < 43008) {                // W3T
        int r = idx - 40960; int k = r >> 5, h = r & 31;
        float G = bn3g[h] / sqrtf(bn3v[h] + 1e-5f);
        ws[W3T_OFF + r] = W3[h * 64 + k] * G;
    } else if (idx < 43072) {                // WoT
        int r = idx - 43008; int k = r >> 1, o = r & 1;
        ws[WOT_OFF + r] = Wo[o * 32 + k];
    }
}

__global__ void prep_bias(const float* __restrict__ bn0g, const float* __restrict__ bn0b,
                          const float* __restrict__ bn0m, const float* __restrict__ bn0v,
                          const float* __restrict__ b1,   const float* __restrict__ W1,
                          const float* __restrict__ bn1g, const float* __restrict__ bn1b,
                          const float* __restrict__ bn1m, const float* __restrict__ bn1v,
                          const float* __restrict__ b2,   const float* __restrict__ bn2g,
                          const float* __restrict__ bn2b, const float* __restrict__ bn2m,
                          const float* __restrict__ bn2v,
                          const float* __restrict__ b3,   const float* __restrict__ bn3g,
                          const float* __restrict__ bn3b, const float* __restrict__ bn3m,
                          const float* __restrict__ bn3v,
                          const float* __restrict__ bo,   float* __restrict__ ws)
{
    __shared__ float Cs[256];
    const int tid = threadIdx.x;
    {
        float A = bn0g[tid] / sqrtf(bn0v[tid] + 1e-5f);
        Cs[tid] = bn0b[tid] - bn0m[tid] * A;   // bn0 applied to x=0
    }
    __syncthreads();
    if (tid < 128) {
        float G  = bn1g[tid] / sqrtf(bn1v[tid] + 1e-5f);
        float Bn = bn1b[tid] - bn1m[tid] * G;
        float s  = b1[tid];
        const float* wr = W1 + tid * 256;
        for (int f = 0; f < 256; ++f) s = fmaf(wr[f], Cs[f], s);
        ws[B1_OFF + tid] = G * s + Bn;
    }
    if (tid < 64) {
        float G = bn2g[tid] / sqrtf(bn2v[tid] + 1e-5f);
        ws[B2_OFF + tid] = G * b2[tid] + (bn2b[tid] - bn2m[tid] * G);
    }
    if (tid < 32) {
        float G = bn3g[tid] / sqrtf(bn3v[tid] + 1e-5f);
        ws[B3_OFF + tid] = G * b3[tid] + (bn3b[tid] - bn3m[tid] * G);
    }
    if (tid < 2) ws[BO_OFF + tid] = bo[tid];
}

// one 16-step LIF scan; packs 16 spikes as bf16 into pk[8] (2 per uint32)
__device__ __forceinline__ void lif16(const float* __restrict__ ur, float& v, float& ii, uint32 pk[8])
{
#pragma unroll
    for (int t = 0; t < 16; t += 2) {
        float vd0 = v + 0.1f * ((0.0f - v) + ii);
        bool  z0  = vd0 > 1.0f;
        v  = z0 ? 0.0f : vd0;
        ii = (ii - 0.2f * ii) + ur[t];
        float vd1 = v + 0.1f * ((0.0f - v) + ii);
        bool  z1  = vd1 > 1.0f;
        v  = z1 ? 0.0f : vd1;
        ii = (ii - 0.2f * ii) + ur[t + 1];
        pk[t >> 1] = (z0 ? 0x3F80u : 0u) | (z1 ? 0x3F800000u : 0u);
    }
}

__global__ __launch_bounds__(256, 3) void snn_main(
    const float* __restrict__ xin, const float* __restrict__ ws, float* __restrict__ out)
{
    __shared__ uint4 lds_u4[LDS_BYTES / 16];
    char* lds = (char*)lds_u4;
    float*   xs  = (float*)(lds + XS_OFF);
    float*   u1T = (float*)(lds + U1_OFF);
    char*    s1T = (char*)(lds + S1_OFF);   // row stride 144 B, 64 bf16 used
    float*   u2T = (float*)(lds + U2_OFF);
    char*    s2T = (char*)(lds + S2_OFF);
    float*   u3T = (float*)(lds + U3_OFF);
    char*    s3T = (char*)(lds + S3_OFF);
    float*   uoT = (float*)(lds + UO_OFF);

    const int tid  = threadIdx.x;
    const int lane = tid & 63;
    const int wv   = tid >> 6;
    const int wvu  = __builtin_amdgcn_readfirstlane(wv); // wave-uniform -> scalar path
    const int sl   = lane >> 4;   // sample 0..3 (GEMM lane mapping)
    const int tl   = lane & 15;   // local t
    const int b0   = blockIdx.x * NS;

    // persistent LIF states (fixed thread->neuron maps across windows)
    float v1a = 0.f, i1a = 0.f, v1b = 0.f, i1b = 0.f;  // layer1: neurons tid, tid+256
    float v2 = 0.f, i2 = 0.f;                          // layer2: neuron tid
    float v3 = 0.f, i3 = 0.f;                          // layer3: neuron tid (tid<128)
    float vo = 0.f, io = 0.f, aspk = 0.f;              // out: tid<8 -> (s=tid>>1,o=tid&1)

    for (int w = 0; w < NWIN; ++w) {
        const int t0 = w * WT;

        // ---------------- layer 1 GEMM:  u1[s][t][h], K=256 in 4 chunks ----------------
        float acc1[32];
        {
            const float* bsrc = ws + B1_OFF + wvu * 32;
#pragma unroll
            for (int j = 0; j < 32; ++j) acc1[j] = bsrc[j];
        }
        for (int c = 0; c < 4; ++c) {
            __syncthreads();
            {   // stage x chunk: thread -> (s = tid>>6, f = c*64 + (tid&63)), 16 t's
                const int ss = tid >> 6;
                const int fr = tid & 63;
                const float* src = xin + ((size_t)(b0 + ss) * F_IN + (c * 64 + fr)) * T_REAL + t0;
                float4 vv[4];
#pragma unroll
                for (int j = 0; j < 4; ++j) {
                    if (t0 + j * 4 < T_REAL) vv[j] = *(const float4*)(src + j * 4);
                    else                     vv[j] = make_float4(0.f, 0.f, 0.f, 0.f);
                }
                float* dst = xs + fr * 72 + ss * 16;
#pragma unroll
                for (int j = 0; j < 4; ++j) ((float4*)dst)[j] = vv[j];
            }
            __syncthreads();
            const float* wbase = ws + W1T_OFF + (c * 64) * NH1 + wvu * 32;
#pragma unroll 2
            for (int k = 0; k < 64; ++k) {
                const float  xv = xs[k * 72 + lane];      // conflict-free: consecutive
                const float* wr = wbase + k * NH1;        // uniform -> s_load
#pragma unroll
                for (int j = 0; j < 32; ++j) acc1[j] = fmaf(wr[j], xv, acc1[j]);
            }
        }
        __syncthreads();            // xs reads done before u1T (overlapping region) write
        {
            const int base = sl * NH1 + wvu * 32;
#pragma unroll
            for (int j = 0; j < 32; ++j) u1T[(base + j) * 17 + tl] = acc1[j];
        }
        __syncthreads();

        // ---------------- LIF 1 (512 neurons, 2/thread) ----------------
        {
            uint32 pk[8];
            {
                const int ss = tid >> 7, hh = tid & 127;
                lif16(u1T + (ss * NH1 + hh) * 17, v1a, i1a, pk);
                *(uint4*)(s1T + hh * 144 + ss * 32)      = make_uint4(pk[0], pk[1], pk[2], pk[3]);
                *(uint4*)(s1T + hh * 144 + ss * 32 + 16) = make_uint4(pk[4], pk[5], pk[6], pk[7]);
            }
            {
                const int nn = tid + 256;
                const int ss = nn >> 7, hh = nn & 127;
                lif16(u1T + (ss * NH1 + hh) * 17, v1b, i1b, pk);
                *(uint4*)(s1T + hh * 144 + ss * 32)      = make_uint4(pk[0], pk[1], pk[2], pk[3]);
                *(uint4*)(s1T + hh * 144 + ss * 32 + 16) = make_uint4(pk[4], pk[5], pk[6], pk[7]);
            }
        }
        __syncthreads();

        // ---------------- layer 2 GEMM (K=128) ----------------
        {
            float acc2[16];
            const float* bsrc = ws + B2_OFF + wvu * 16;
#pragma unroll
            for (int j = 0; j < 16; ++j) acc2[j] = bsrc[j];
            const float* wbase = ws + W2T_OFF + wvu * 16;
#pragma unroll 2
            for (int k = 0; k < NH1; ++k) {
                const float xv = __uint_as_float((uint32)*(const ushortT*)(s1T + k * 144 + lane * 2) << 16);
                const float* wr = wbase + k * NH2;
#pragma unroll
                for (int j = 0; j < 16; ++j) acc2[j] = fmaf(wr[j], xv, acc2[j]);
            }
            const int base = sl * NH2 + wvu * 16;       // u2T disjoint from s1T: safe pre-sync
#pragma unroll
            for (int j = 0; j < 16; ++j) u2T[(base + j) * 17 + tl] = acc2[j];
        }
        __syncthreads();

        // ---------------- LIF 2 (256 neurons) ----------------
        {
            uint32 pk[8];
            const int ss = tid >> 6, hh = tid & 63;
            lif16(u2T + (ss * NH2 + hh) * 17, v2, i2, pk);
            *(uint4*)(s2T + hh * 144 + ss * 32)      = make_uint4(pk[0], pk[1], pk[2], pk[3]);
            *(uint4*)(s2T + hh * 144 + ss * 32 + 16) = make_uint4(pk[4], pk[5], pk[6], pk[7]);
        }
        __syncthreads();

        // ---------------- layer 3 GEMM (K=64) ----------------
        {
            float acc3[8];
            const float* bsrc = ws + B3_OFF + wvu * 8;
#pragma unroll
            for (int j = 0; j < 8; ++j) acc3[j] = bsrc[j];
            const float* wbase = ws + W3T_OFF + wvu * 8;
#pragma unroll 2
            for (int k = 0; k < NH2; ++k) {
                const float xv = __uint_as_float((uint32)*(const ushortT*)(s2T + k * 144 + lane * 2) << 16);
                const float* wr = wbase + k * NH3;
#pragma unroll
                for (int j = 0; j < 8; ++j) acc3[j] = fmaf(wr[j], xv, acc3[j]);
            }
            const int base = sl * NH3 + wvu * 8;
#pragma unroll
            for (int j = 0; j < 8; ++j) u3T[(base + j) * 17 + tl] = acc3[j];
        }
        __syncthreads();

        // ---------------- LIF 3 (128 neurons) ----------------
        if (tid < 128) {
            uint32 pk[8];
            const int ss = tid >> 5, hh = tid & 31;
            lif16(u3T + (ss * NH3 + hh) * 17, v3, i3, pk);
            *(uint4*)(s3T + hh * 144 + ss * 32)      = make_uint4(pk[0], pk[1], pk[2], pk[3]);
            *(uint4*)(s3T + hh * 144 + ss * 32 + 16) = make_uint4(pk[4], pk[5], pk[6], pk[7]);
        }
        __syncthreads();

        // ---------------- output GEMM (K=32, wave 0 only) ----------------
        if (wv == 0) {
            float ao0 = ws[BO_OFF + 0], ao1 = ws[BO_OFF + 1];
            for (int k = 0; k < NH3; ++k) {
                const float xv = __uint_as_float((uint32)*(const ushortT*)(s3T + k * 144 + lane * 2) << 16);
                ao0 = fmaf(ws[WOT_OFF + k * 2 + 0], xv, ao0);
                ao1 = fmaf(ws[WOT_OFF + k * 2 + 1], xv, ao1);
            }
            uoT[(sl * 2 + 0) * 17 + tl] = ao0;
            uoT[(sl * 2 + 1) * 17 + tl] = ao1;
        }
        __syncthreads();

        // ---------------- output LIF + accumulate (guard t<100) ----------------
        if (tid < 8) {
            const int ss = tid >> 1, oo = tid & 1;
            const float* ur = uoT + (ss * 2 + oo) * 17;
            float v = vo, ii = io, a = aspk;
#pragma unroll
            for (int t = 0; t < 16; ++t) {
                float vd = v + 0.1f * ((0.0f - v) + ii);
                bool  z  = vd > 1.0f;
                v  = z ? 0.0f : vd;
                ii = (ii - 0.2f * ii) + ur[t];
                if (t0 + t < T_REAL) a += z ? 1.0f : 0.0f;
            }
            vo = v; io = ii; aspk = a;
        }
        // next window's first __syncthreads (chunk loop) protects xs overwrite
    }

    if (tid < 8) out[(size_t)(b0 + (tid >> 1)) * 2 + (tid & 1)] = aspk;
}

extern "C" void kernel_launch(void* const* d_in, const int* in_sizes, int n_in,
                              void* d_out, int out_size, void* d_ws, size_t ws_size,
                              hipStream_t stream)
{
    const float* x    = (const float*)d_in[0];
    const float* bn0g = (const float*)d_in[1];
    const float* bn0b = (const float*)d_in[2];
    const float* bn0m = (const float*)d_in[3];
    const float* bn0v = (const float*)d_in[4];
    const float* W1   = (const float*)d_in[5];
    const float* b1   = (const float*)d_in[6];
    const float* bn1g = (const float*)d_in[7];
    const float* bn1b = (const float*)d_in[8];
    const float* bn1m = (const float*)d_in[9];
    const float* bn1v = (const float*)d_in[10];
    const float* W2   = (const float*)d_in[11];
    const float* b2   = (const float*)d_in[12];
    const float* bn2g = (const float*)d_in[13];
    const float* bn2b = (const float*)d_in[14];
    const float* bn2m = (const float*)d_in[15];
    const float* bn2v = (const float*)d_in[16];
    const float* W3   = (const float*)d_in[17];
    const float* b3   = (const float*)d_in[18];
    const float* bn3g = (const float*)d_in[19];
    const float* bn3b = (const float*)d_in[20];
    const float* bn3m = (const float*)d_in[21];
    const float* bn3v = (const float*)d_in[22];
    const float* Wo   = (const float*)d_in[23];
    const float* bo   = (const float*)d_in[24];
    float* ws  = (float*)d_ws;
    float* pout = (float*)d_out;

    prep_w<<<169, 256, 0, stream>>>(W1, W2, W3, Wo, bn0g, bn0v, bn1g, bn1v,
                                    bn2g, bn2v, bn3g, bn3v, ws);
    prep_bias<<<1, 256, 0, stream>>>(bn0g, bn0b, bn0m, bn0v, b1, W1,
                                     bn1g, bn1b, bn1m, bn1v,
                                     b2, bn2g, bn2b, bn2m, bn2v,
                                     b3, bn3g, bn3b, bn3m, bn3v, bo, ws);
    snn_main<<<1024, 256, 0, stream>>>(x, ws, pout);
}

// Round 4
// 1052.334 us; speedup vs baseline: 2.6886x; 2.6886x over previous
//
#include <hip/hip_runtime.h>
#include <stdint.h>

typedef unsigned int   uint32;
typedef unsigned short ushortT;
typedef short bf16x8 __attribute__((ext_vector_type(8)));
typedef float f32x4  __attribute__((ext_vector_type(4)));

#define T_REAL 100

// ---- workspace layout ----
// short (bf16-bit) region:
#define W1S 0          // 3 x [128][256]
#define W2S 98304      // 3 x [64][128]
#define W3S 122880     // 3 x [32][64]
#define WOS 129024     // 3 x [16][32] (rows 2..15 zero)
// float region (dword offsets into ws):
#define B1F 65280
#define B2F 65408
#define B3F 65472
#define BOF 65504

// ---- LDS layout (bytes) ----
// region A (base 0): Xw [64][264]bf16 s=528 -> 33792 ; then s1 [64][136] s=272 ;
//                    then s2 [64][72] s=144 ; then s3 [64][40] s=80 (sequenced reuse)
// region B (base 33792): u1 [512][17]f32 = 34816 ; then u2/u3/uo (sequenced reuse)
#define UB_BASE 33792
#define LDS_BYTES 68608

#define MFMA(a,b,c) __builtin_amdgcn_mfma_f32_16x16x32_bf16(a,b,c,0,0,0)

__device__ __forceinline__ ushortT bf16rne(float x) {
    uint32 u = __float_as_uint(x);
    return (ushortT)((u + 0x7FFFu + ((u >> 16) & 1u)) >> 16);
}

// exact 3-way split: w == hi + mid + lo in fp32
__device__ __forceinline__ void split3(float w, ushortT& a, ushortT& b, ushortT& c) {
    a = bf16rne(w); float fa = __uint_as_float((uint32)a << 16);
    float r1 = w - fa;
    b = bf16rne(r1); float fb = __uint_as_float((uint32)b << 16);
    float r2 = r1 - fb;
    c = bf16rne(r2);
}

__global__ void prep_w(const float* __restrict__ W1, const float* __restrict__ W2,
                       const float* __restrict__ W3, const float* __restrict__ Wo,
                       const float* __restrict__ bn0g, const float* __restrict__ bn0v,
                       const float* __restrict__ bn1g, const float* __restrict__ bn1v,
                       const float* __restrict__ bn2g, const float* __restrict__ bn2v,
                       const float* __restrict__ bn3g, const float* __restrict__ bn3v,
                       ushortT* __restrict__ wsS)
{
    int idx = blockIdx.x * 256 + threadIdx.x;
    float w; int base, size, off;
    if (idx < 32768) {                 // W1 [128][256] * A[f] * G1[h]
        int h = idx >> 8, f = idx & 255;
        float A = bn0g[f] / sqrtf(bn0v[f] + 1e-5f);
        float G = bn1g[h] / sqrtf(bn1v[h] + 1e-5f);
        w = W1[idx] * A * G; base = W1S; size = 32768; off = idx;
    } else if (idx < 40960) {          // W2 [64][128] * G2[h]
        int r = idx - 32768; int h = r >> 7;
        float G = bn2g[h] / sqrtf(bn2v[h] + 1e-5f);
        w = W2[r] * G; base = W2S; size = 8192; off = r;
    } else if (idx < 43008) {          // W3 [32][64] * G3[h]
        int r = idx - 40960; int h = r >> 6;
        float G = bn3g[h] / sqrtf(bn3v[h] + 1e-5f);
        w = W3[r] * G; base = W3S; size = 2048; off = r;
    } else if (idx < 43520) {          // Wo padded [16][32]
        int r = idx - 43008; int o = r >> 5, k = r & 31;
        w = (o < 2) ? Wo[o * 32 + k] : 0.f;
        base = WOS; size = 512; off = r;
    } else return;
    ushortT a, b, c; split3(w, a, b, c);
    wsS[base + off] = a; wsS[base + size + off] = b; wsS[base + 2 * size + off] = c;
}

__global__ void prep_bias(const float* __restrict__ bn0g, const float* __restrict__ bn0b,
                          const float* __restrict__ bn0m, const float* __restrict__ bn0v,
                          const float* __restrict__ b1,   const float* __restrict__ W1,
                          const float* __restrict__ bn1g, const float* __restrict__ bn1b,
                          const float* __restrict__ bn1m, const float* __restrict__ bn1v,
                          const float* __restrict__ b2,   const float* __restrict__ bn2g,
                          const float* __restrict__ bn2b, const float* __restrict__ bn2m,
                          const float* __restrict__ bn2v,
                          const float* __restrict__ b3,   const float* __restrict__ bn3g,
                          const float* __restrict__ bn3b, const float* __restrict__ bn3m,
                          const float* __restrict__ bn3v,
                          const float* __restrict__ bo,   float* __restrict__ wsF)
{
    __shared__ float Cs[256];
    const int tid = threadIdx.x;
    {
        float A = bn0g[tid] / sqrtf(bn0v[tid] + 1e-5f);
        Cs[tid] = bn0b[tid] - bn0m[tid] * A;   // BN0 applied to x=0
    }
    __syncthreads();
    if (tid < 128) {
        float G  = bn1g[tid] / sqrtf(bn1v[tid] + 1e-5f);
        float Bn = bn1b[tid] - bn1m[tid] * G;
        float s  = b1[tid];
        const float* wr = W1 + tid * 256;
        for (int f = 0; f < 256; ++f) s = fmaf(wr[f], Cs[f], s);
        wsF[B1F + tid] = G * s + Bn;
    }
    if (tid < 64) {
        float G = bn2g[tid] / sqrtf(bn2v[tid] + 1e-5f);
        wsF[B2F + tid] = G * b2[tid] + (bn2b[tid] - bn2m[tid] * G);
    }
    if (tid < 32) {
        float G = bn3g[tid] / sqrtf(bn3v[tid] + 1e-5f);
        wsF[B3F + tid] = G * b3[tid] + (bn3b[tid] - bn3m[tid] * G);
    }
    if (tid < 2) wsF[BOF + tid] = bo[tid];
}

__global__ __launch_bounds__(256, 2) void snn_main(
    const float* __restrict__ xin,
    const ushortT* __restrict__ wsS,
    const float* __restrict__ wsF,
    float* __restrict__ out)
{
    __shared__ uint4 ldsq[LDS_BYTES / 16];
    char* lds = (char*)ldsq;
    char* xw = lds;                 // [64][264] bf16, row stride 528 B
    char* s1 = lds;                 // [64][136] bf16, 272 B (after Xw dead)
    char* s2 = lds;                 // [64][72]  bf16, 144 B
    char* s3 = lds;                 // [64][40]  bf16, 80 B
    float* u1 = (float*)(lds + UB_BASE);   // [512][17] f32
    float* u2 = u1;                 // [256][17]
    float* u3 = u1;                 // [128][17]
    float* uo = u1;                 // [8][17]

    const int tid  = threadIdx.x;
    const int lane = tid & 63;
    const int wv   = tid >> 6;
    const int wvu  = __builtin_amdgcn_readfirstlane(wv);
    const int lr   = lane & 15;    // MFMA in-tile row/col
    const int lg   = lane >> 4;    // MFMA k-group / t-group
    const int b0   = blockIdx.x * 4;

    // gather mapping: wave = sample; lane -> (f-slot, t-quarter)
    const int gm = lane >> 2;
    const int gq = lane & 3;
    const float* xbase = xin + (size_t)(b0 + wvu) * 256 * 100;

    float4 xr[16];
#pragma unroll
    for (int i = 0; i < 16; ++i) {            // prologue: window 0 (all t valid)
        const int f = i * 16 + gm;
        xr[i] = *(const float4*)(xbase + f * 100 + gq * 4);
    }

    // persistent LIF states
    float v1a = 0, i1a = 0, v1b = 0, i1b = 0; // L1: (s=wv, h=2*lane, 2*lane+1)
    float v2a = 0, i2a = 0, v2b = 0, i2b = 0; // L2: lane<32, (s=wv, h=2*lane,+1)
    float v3a = 0, i3a = 0, v3b = 0, i3b = 0; // L3: lane<16
    float vo = 0, io = 0, aspk = 0;           // out: tid<8 -> (s=tid>>1, o=tid&1)

#pragma unroll 1
    for (int w = 0; w < 7; ++w) {
        const int t0 = w * 16;
        __syncthreads();                      // region A free (prev Lout reads done)

        // ---- stage Xw (bf16 transpose-scatter; spikes exact in bf16) ----
#pragma unroll
        for (int i = 0; i < 16; ++i) {
            const int f = i * 16 + gm;
            char* colp = xw + f * 2;
            const int r0 = wvu * 16 + gq * 4;
            *(ushortT*)(colp + (size_t)(r0 + 0) * 528) = (ushortT)(__float_as_uint(xr[i].x) >> 16);
            *(ushortT*)(colp + (size_t)(r0 + 1) * 528) = (ushortT)(__float_as_uint(xr[i].y) >> 16);
            *(ushortT*)(colp + (size_t)(r0 + 2) * 528) = (ushortT)(__float_as_uint(xr[i].z) >> 16);
            *(ushortT*)(colp + (size_t)(r0 + 3) * 528) = (ushortT)(__float_as_uint(xr[i].w) >> 16);
        }
        __syncthreads();

        // ---- prefetch next window's gather (hidden under MFMA below) ----
        if (w < 6) {
            const int t0n = t0 + 16;
            const bool okq = (t0n + gq * 4) < T_REAL;
#pragma unroll
            for (int i = 0; i < 16; ++i) {
                const int f = i * 16 + gm;
                if (okq) xr[i] = *(const float4*)(xbase + f * 100 + t0n + gq * 4);
                else     xr[i] = make_float4(0.f, 0.f, 0.f, 0.f);
            }
        }

        // ---- L1 GEMM: [64 x 256] x [256 x 128], wave col-split (32 cols) ----
        {
            const int cb = wvu * 32;
            f32x4 acc[4][2];
            const float bia0 = wsF[B1F + cb + lr];
            const float bia1 = wsF[B1F + cb + 16 + lr];
#pragma unroll
            for (int rt = 0; rt < 4; ++rt) {
                acc[rt][0] = (f32x4){bia0, bia0, bia0, bia0};
                acc[rt][1] = (f32x4){bia1, bia1, bia1, bia1};
            }
#pragma unroll
            for (int ks = 0; ks < 8; ++ks) {
                const int koff = ks * 32 + lg * 8;
                const ushortT* wb0 = wsS + W1S + (cb + lr) * 256 + koff;
                const ushortT* wb1 = wb0 + 16 * 256;
                bf16x8 B00 = *(const bf16x8*)(wb0);
                bf16x8 B01 = *(const bf16x8*)(wb0 + 32768);
                bf16x8 B02 = *(const bf16x8*)(wb0 + 65536);
                bf16x8 B10 = *(const bf16x8*)(wb1);
                bf16x8 B11 = *(const bf16x8*)(wb1 + 32768);
                bf16x8 B12 = *(const bf16x8*)(wb1 + 65536);
#pragma unroll
                for (int rt = 0; rt < 4; ++rt) {
                    bf16x8 A = *(const bf16x8*)(xw + (size_t)(rt * 16 + lr) * 528 + koff * 2);
                    acc[rt][0] = MFMA(A, B00, acc[rt][0]);
                    acc[rt][1] = MFMA(A, B10, acc[rt][1]);
                    acc[rt][0] = MFMA(A, B01, acc[rt][0]);
                    acc[rt][1] = MFMA(A, B11, acc[rt][1]);
                    acc[rt][0] = MFMA(A, B02, acc[rt][0]);
                    acc[rt][1] = MFMA(A, B12, acc[rt][1]);
                }
            }
#pragma unroll
            for (int rt = 0; rt < 4; ++rt)
#pragma unroll
                for (int ct = 0; ct < 2; ++ct) {
                    float* up = u1 + (size_t)(rt * 128 + cb + ct * 16 + lr) * 17 + lg * 4;
#pragma unroll
                    for (int j = 0; j < 4; ++j) up[j] = acc[rt][ct][j];
                }
        }
        __syncthreads();

        // ---- LIF1: 512 neurons, 2/thread, pack spike bf16-pairs -> s1 ----
        {
            const float* uA = u1 + (size_t)(wvu * 128 + 2 * lane) * 17;
            const float* uB = uA + 17;
            char* dst = s1 + (size_t)(wvu * 16) * 272 + lane * 4;
            float vA = v1a, iA = i1a, vB = v1b, iB = i1b;
#pragma unroll
            for (int t = 0; t < 16; ++t) {
                float vdA = vA + 0.1f * ((0.0f - vA) + iA); bool zA = vdA > 1.0f;
                vA = zA ? 0.0f : vdA; iA = (iA - 0.2f * iA) + uA[t];
                float vdB = vB + 0.1f * ((0.0f - vB) + iB); bool zB = vdB > 1.0f;
                vB = zB ? 0.0f : vdB; iB = (iB - 0.2f * iB) + uB[t];
                *(uint32*)(dst + t * 272) = (zA ? 0x3F80u : 0u) | (zB ? 0x3F800000u : 0u);
            }
            v1a = vA; i1a = iA; v1b = vB; i1b = iB;
        }
        __syncthreads();

        // ---- L2 GEMM: [64 x 128] x [128 x 64], wave col-split (16 cols) ----
        {
            const int cb = wvu * 16;
            f32x4 acc[4];
            const float bia = wsF[B2F + cb + lr];
#pragma unroll
            for (int rt = 0; rt < 4; ++rt) acc[rt] = (f32x4){bia, bia, bia, bia};
#pragma unroll
            for (int ks = 0; ks < 4; ++ks) {
                const int koff = ks * 32 + lg * 8;
                const ushortT* wb = wsS + W2S + (cb + lr) * 128 + koff;
                bf16x8 Bh = *(const bf16x8*)(wb);
                bf16x8 Bm = *(const bf16x8*)(wb + 8192);
                bf16x8 Bl = *(const bf16x8*)(wb + 16384);
#pragma unroll
                for (int rt = 0; rt < 4; ++rt) {
                    bf16x8 A = *(const bf16x8*)(s1 + (size_t)(rt * 16 + lr) * 272 + koff * 2);
                    acc[rt] = MFMA(A, Bh, acc[rt]);
                    acc[rt] = MFMA(A, Bm, acc[rt]);
                    acc[rt] = MFMA(A, Bl, acc[rt]);
                }
            }
#pragma unroll
            for (int rt = 0; rt < 4; ++rt) {
                float* up = u2 + (size_t)(rt * 64 + cb + lr) * 17 + lg * 4;
#pragma unroll
                for (int j = 0; j < 4; ++j) up[j] = acc[rt][j];
            }
        }
        __syncthreads();

        // ---- LIF2: 256 neurons, lanes<32, all waves ----
        if (lane < 32) {
            const float* uA = u2 + (size_t)(wvu * 64 + 2 * lane) * 17;
            const float* uB = uA + 17;
            char* dst = s2 + (size_t)(wvu * 16) * 144 + lane * 4;
            float vA = v2a, iA = i2a, vB = v2b, iB = i2b;
#pragma unroll
            for (int t = 0; t < 16; ++t) {
                float vdA = vA + 0.1f * ((0.0f - vA) + iA); bool zA = vdA > 1.0f;
                vA = zA ? 0.0f : vdA; iA = (iA - 0.2f * iA) + uA[t];
                float vdB = vB + 0.1f * ((0.0f - vB) + iB); bool zB = vdB > 1.0f;
                vB = zB ? 0.0f : vdB; iB = (iB - 0.2f * iB) + uB[t];
                *(uint32*)(dst + t * 144) = (zA ? 0x3F80u : 0u) | (zB ? 0x3F800000u : 0u);
            }
            v2a = vA; i2a = iA; v2b = vB; i2b = iB;
        }
        __syncthreads();

        // ---- L3 GEMM: [64 x 64] x [64 x 32], waves 2x2 (rows x cols) ----
        {
            const int rhu = wvu >> 1, chu = wvu & 1;
            const int cb = chu * 16;
            f32x4 acc[2];
            const float bia = wsF[B3F + cb + lr];
            acc[0] = (f32x4){bia, bia, bia, bia};
            acc[1] = (f32x4){bia, bia, bia, bia};
#pragma unroll
            for (int ks = 0; ks < 2; ++ks) {
                const int koff = ks * 32 + lg * 8;
                const ushortT* wb = wsS + W3S + (cb + lr) * 64 + koff;
                bf16x8 Bh = *(const bf16x8*)(wb);
                bf16x8 Bm = *(const bf16x8*)(wb + 2048);
                bf16x8 Bl = *(const bf16x8*)(wb + 4096);
#pragma unroll
                for (int r = 0; r < 2; ++r) {
                    bf16x8 A = *(const bf16x8*)(s2 + (size_t)((rhu * 2 + r) * 16 + lr) * 144 + koff * 2);
                    acc[r] = MFMA(A, Bh, acc[r]);
                    acc[r] = MFMA(A, Bm, acc[r]);
                    acc[r] = MFMA(A, Bl, acc[r]);
                }
            }
#pragma unroll
            for (int r = 0; r < 2; ++r) {
                float* up = u3 + (size_t)((rhu * 2 + r) * 32 + cb + lr) * 17 + lg * 4;
#pragma unroll
                for (int j = 0; j < 4; ++j) up[j] = acc[r][j];
            }
        }
        __syncthreads();

        // ---- LIF3: 128 neurons, lanes<16, all waves ----
        if (lane < 16) {
            const float* uA = u3 + (size_t)(wvu * 32 + 2 * lane) * 17;
            const float* uB = uA + 17;
            char* dst = s3 + (size_t)(wvu * 16) * 80 + lane * 4;
            float vA = v3a, iA = i3a, vB = v3b, iB = i3b;
#pragma unroll
            for (int t = 0; t < 16; ++t) {
                float vdA = vA + 0.1f * ((0.0f - vA) + iA); bool zA = vdA > 1.0f;
                vA = zA ? 0.0f : vdA; iA = (iA - 0.2f * iA) + uA[t];
                float vdB = vB + 0.1f * ((0.0f - vB) + iB); bool zB = vdB > 1.0f;
                vB = zB ? 0.0f : vdB; iB = (iB - 0.2f * iB) + uB[t];
                *(uint32*)(dst + t * 80) = (zA ? 0x3F80u : 0u) | (zB ? 0x3F800000u : 0u);
            }
            v3a = vA; i3a = iA; v3b = vB; i3b = iB;
        }
        __syncthreads();

        // ---- Lout GEMM: [64 x 32] x [32 x 16(2 real)], wave row-split ----
        {
            const float bia = (lr < 2) ? wsF[BOF + lr] : 0.f;
            f32x4 acc = (f32x4){bia, bia, bia, bia};
            const int koff = lg * 8;
            const ushortT* wb = wsS + WOS + lr * 32 + koff;
            bf16x8 Bh = *(const bf16x8*)(wb);
            bf16x8 Bm = *(const bf16x8*)(wb + 512);
            bf16x8 Bl = *(const bf16x8*)(wb + 1024);
            bf16x8 A = *(const bf16x8*)(s3 + (size_t)(wvu * 16 + lr) * 80 + koff * 2);
            acc = MFMA(A, Bh, acc);
            acc = MFMA(A, Bm, acc);
            acc = MFMA(A, Bl, acc);
            if (lr < 2) {
                float* up = uo + (size_t)(wvu * 2 + lr) * 17 + lg * 4;
#pragma unroll
                for (int j = 0; j < 4; ++j) up[j] = acc[j];
            }
        }
        __syncthreads();

        // ---- LIF out + accumulate (t<100 guard) ----
        if (tid < 8) {
            const float* ur = uo + tid * 17;
            float v = vo, ii = io, a = aspk;
#pragma unroll
            for (int t = 0; t < 16; ++t) {
                float vd = v + 0.1f * ((0.0f - v) + ii);
                bool z = vd > 1.0f; v = z ? 0.0f : vd;
                ii = (ii - 0.2f * ii) + ur[t];
                if (t0 + t < T_REAL) a += z ? 1.0f : 0.0f;
            }
            vo = v; io = ii; aspk = a;
        }
    }

    if (tid < 8) out[(size_t)(b0 + (tid >> 1)) * 2 + (tid & 1)] = aspk;
}

extern "C" void kernel_launch(void* const* d_in, const int* in_sizes, int n_in,
                              void* d_out, int out_size, void* d_ws, size_t ws_size,
                              hipStream_t stream)
{
    const float* x    = (const float*)d_in[0];
    const float* bn0g = (const float*)d_in[1];
    const float* bn0b = (const float*)d_in[2];
    const float* bn0m = (const float*)d_in[3];
    const float* bn0v = (const float*)d_in[4];
    const float* W1   = (const float*)d_in[5];
    const float* b1   = (const float*)d_in[6];
    const float* bn1g = (const float*)d_in[7];
    const float* bn1b = (const float*)d_in[8];
    const float* bn1m = (const float*)d_in[9];
    const float* bn1v = (const float*)d_in[10];
    const float* W2   = (const float*)d_in[11];
    const float* b2   = (const float*)d_in[12];
    const float* bn2g = (const float*)d_in[13];
    const float* bn2b = (const float*)d_in[14];
    const float* bn2m = (const float*)d_in[15];
    const float* bn2v = (const float*)d_in[16];
    const float* W3   = (const float*)d_in[17];
    const float* b3   = (const float*)d_in[18];
    const float* bn3g = (const float*)d_in[19];
    const float* bn3b = (const float*)d_in[20];
    const float* bn3m = (const float*)d_in[21];
    const float* bn3v = (const float*)d_in[22];
    const float* Wo   = (const float*)d_in[23];
    const float* bo   = (const float*)d_in[24];

    ushortT* wsS = (ushortT*)d_ws;
    float*   wsF = (float*)d_ws;
    float*   pout = (float*)d_out;

    prep_w<<<170, 256, 0, stream>>>(W1, W2, W3, Wo, bn0g, bn0v, bn1g, bn1v,
                                    bn2g, bn2v, bn3g, bn3v, wsS);
    prep_bias<<<1, 256, 0, stream>>>(bn0g, bn0b, bn0m, bn0v, b1, W1,
                                     bn1g, bn1b, bn1m, bn1v,
                                     b2, bn2g, bn2b, bn2m, bn2v,
                                     b3, bn3g, bn3b, bn3m, bn3v, bo, wsF);
    snn_main<<<1024, 256, 0, stream>>>(x, wsS, wsF, pout);
}

// Round 5
// 1035.721 us; speedup vs baseline: 2.7317x; 1.0160x over previous
//
#include <hip/hip_runtime.h>
#include <stdint.h>

typedef unsigned int   uint32;
typedef unsigned short ushortT;
typedef short bf16x8 __attribute__((ext_vector_type(8)));
typedef float f32x4  __attribute__((ext_vector_type(4)));

#define T_REAL 100

// ---- workspace layout ----
// short (bf16-bit) region:
#define W1S 0          // 3 x [128][256]
#define W2S 98304      // 3 x [64][128]
#define W3S 122880     // 3 x [32][64]
#define WOS 129024     // 3 x [16][32] (rows 2..15 zero)
// float region (dword offsets into ws):
#define B1F 65280
#define B2F 65408
#define B3F 65472
#define BOF 65504

// ---- LDS layout (bytes) ----
// region A (base 0): Xw [64][264]bf16 s=528 -> 33792 ; then s1 [64][136] s=272 ;
//                    then s2 [64][72] s=144 ; then s3 [64][40] s=80 (sequenced reuse)
// region B (base 33792): u1 [512][17]f32 = 34816 ; then u2/u3/uo (sequenced reuse)
// region C (base 68608): spike bitmask [4 s][100 t][8 u32] = 12800 (persistent)
#define UB_BASE 33792
#define MK_BASE 68608
#define LDS_BYTES 81408   // x2 blocks/CU = 162816 <= 163840

#define MFMA(a,b,c) __builtin_amdgcn_mfma_f32_16x16x32_bf16(a,b,c,0,0,0)

__device__ __forceinline__ ushortT bf16rne(float x) {
    uint32 u = __float_as_uint(x);
    return (ushortT)((u + 0x7FFFu + ((u >> 16) & 1u)) >> 16);
}

// exact 3-way split: w == hi + mid + lo in fp32
__device__ __forceinline__ void split3(float w, ushortT& a, ushortT& b, ushortT& c) {
    a = bf16rne(w); float fa = __uint_as_float((uint32)a << 16);
    float r1 = w - fa;
    b = bf16rne(r1); float fb = __uint_as_float((uint32)b << 16);
    float r2 = r1 - fb;
    c = bf16rne(r2);
}

__global__ void prep_w(const float* __restrict__ W1, const float* __restrict__ W2,
                       const float* __restrict__ W3, const float* __restrict__ Wo,
                       const float* __restrict__ bn0g, const float* __restrict__ bn0v,
                       const float* __restrict__ bn1g, const float* __restrict__ bn1v,
                       const float* __restrict__ bn2g, const float* __restrict__ bn2v,
                       const float* __restrict__ bn3g, const float* __restrict__ bn3v,
                       ushortT* __restrict__ wsS)
{
    int idx = blockIdx.x * 256 + threadIdx.x;
    float w; int base, size, off;
    if (idx < 32768) {                 // W1 [128][256] * A[f] * G1[h]
        int h = idx >> 8, f = idx & 255;
        float A = bn0g[f] / sqrtf(bn0v[f] + 1e-5f);
        float G = bn1g[h] / sqrtf(bn1v[h] + 1e-5f);
        w = W1[idx] * A * G; base = W1S; size = 32768; off = idx;
    } else if (idx < 40960) {          // W2 [64][128] * G2[h]
        int r = idx - 32768; int h = r >> 7;
        float G = bn2g[h] / sqrtf(bn2v[h] + 1e-5f);
        w = W2[r] * G; base = W2S; size = 8192; off = r;
    } else if (idx < 43008) {          // W3 [32][64] * G3[h]
        int r = idx - 40960; int h = r >> 6;
        float G = bn3g[h] / sqrtf(bn3v[h] + 1e-5f);
        w = W3[r] * G; base = W3S; size = 2048; off = r;
    } else if (idx < 43520) {          // Wo padded [16][32]
        int r = idx - 43008; int o = r >> 5, k = r & 31;
        w = (o < 2) ? Wo[o * 32 + k] : 0.f;
        base = WOS; size = 512; off = r;
    } else return;
    ushortT a, b, c; split3(w, a, b, c);
    wsS[base + off] = a; wsS[base + size + off] = b; wsS[base + 2 * size + off] = c;
}

__global__ void prep_bias(const float* __restrict__ bn0g, const float* __restrict__ bn0b,
                          const float* __restrict__ bn0m, const float* __restrict__ bn0v,
                          const float* __restrict__ b1,   const float* __restrict__ W1,
                          const float* __restrict__ bn1g, const float* __restrict__ bn1b,
                          const float* __restrict__ bn1m, const float* __restrict__ bn1v,
                          const float* __restrict__ b2,   const float* __restrict__ bn2g,
                          const float* __restrict__ bn2b, const float* __restrict__ bn2m,
                          const float* __restrict__ bn2v,
                          const float* __restrict__ b3,   const float* __restrict__ bn3g,
                          const float* __restrict__ bn3b, const float* __restrict__ bn3m,
                          const float* __restrict__ bn3v,
                          const float* __restrict__ bo,   float* __restrict__ wsF)
{
    __shared__ float Cs[256];
    const int tid = threadIdx.x;
    {
        float A = bn0g[tid] / sqrtf(bn0v[tid] + 1e-5f);
        Cs[tid] = bn0b[tid] - bn0m[tid] * A;   // BN0 applied to x=0
    }
    __syncthreads();
    if (tid < 128) {
        float G  = bn1g[tid] / sqrtf(bn1v[tid] + 1e-5f);
        float Bn = bn1b[tid] - bn1m[tid] * G;
        float s  = b1[tid];
        const float* wr = W1 + tid * 256;
        for (int f = 0; f < 256; ++f) s = fmaf(wr[f], Cs[f], s);
        wsF[B1F + tid] = G * s + Bn;
    }
    if (tid < 64) {
        float G = bn2g[tid] / sqrtf(bn2v[tid] + 1e-5f);
        wsF[B2F + tid] = G * b2[tid] + (bn2b[tid] - bn2m[tid] * G);
    }
    if (tid < 32) {
        float G = bn3g[tid] / sqrtf(bn3v[tid] + 1e-5f);
        wsF[B3F + tid] = G * b3[tid] + (bn3b[tid] - bn3m[tid] * G);
    }
    if (tid < 2) wsF[BOF + tid] = bo[tid];
}

__global__ __launch_bounds__(256, 2) void snn_main(
    const float* __restrict__ xin,
    const ushortT* __restrict__ wsS,
    const float* __restrict__ wsF,
    float* __restrict__ out)
{
    __shared__ uint4 ldsq[LDS_BYTES / 16];
    char* lds = (char*)ldsq;
    char* xw = lds;                 // [64][264] bf16, row stride 528 B
    char* s1 = lds;                 // [64][136] bf16, 272 B (after Xw dead)
    char* s2 = lds;                 // [64][72]  bf16, 144 B
    char* s3 = lds;                 // [64][40]  bf16, 80 B
    float* u1 = (float*)(lds + UB_BASE);   // [512][17] f32
    float* u2 = u1;                 // [256][17]
    float* u3 = u1;                 // [128][17]
    float* uo = u1;                 // [8][17]
    uint32* mk = (uint32*)(lds + MK_BASE); // [4][100][8] spike bits (bit f&31 of word f>>5)

    const int tid  = threadIdx.x;
    const int lane = tid & 63;
    const int wv   = tid >> 6;
    const int wvu  = __builtin_amdgcn_readfirstlane(wv);
    const int lr   = lane & 15;    // MFMA in-tile row/col
    const int lg   = lane >> 4;    // MFMA k-group / t-group
    const int b0   = blockIdx.x * 4;

    // ---- stage spike bitmask once: wave = feature-group, lane = feature ----
    {
        const int fg = wvu;                      // features fg*64 .. fg*64+63
        for (int s = 0; s < 4; ++s) {
            const float* rp = xin + ((size_t)(b0 + s) * 256 + fg * 64 + lane) * T_REAL;
            uint32* mrow = mk + (size_t)(s * 100) * 8 + fg * 2 + (lane >> 5);
#pragma unroll 1
            for (int q = 0; q < 25; ++q) {
                float4 v = *(const float4*)(rp + q * 4);
                unsigned long long bx = __ballot(v.x > 0.5f);
                unsigned long long by = __ballot(v.y > 0.5f);
                unsigned long long bz = __ballot(v.z > 0.5f);
                unsigned long long bw = __ballot(v.w > 0.5f);
                if ((lane & 31) == 0) {
                    const int sh = (lane >> 5) * 32;
                    mrow[(q * 4 + 0) * 8] = (uint32)(bx >> sh);
                    mrow[(q * 4 + 1) * 8] = (uint32)(by >> sh);
                    mrow[(q * 4 + 2) * 8] = (uint32)(bz >> sh);
                    mrow[(q * 4 + 3) * 8] = (uint32)(bw >> sh);
                }
            }
        }
    }

    // persistent LIF states
    float v1a = 0, i1a = 0, v1b = 0, i1b = 0; // L1: (s=wv, h=2*lane, 2*lane+1)
    float v2a = 0, i2a = 0, v2b = 0, i2b = 0; // L2: lane<32, (s=wv, h=2*lane,+1)
    float v3a = 0, i3a = 0, v3b = 0, i3b = 0; // L3: lane<16
    float vo = 0, io = 0, aspk = 0;           // out: tid<8 -> (s=tid>>1, o=tid&1)

#pragma unroll 1
    for (int w = 0; w < 7; ++w) {
        const int t0 = w * 16;
        __syncthreads();     // staging done (w=0) / region A + mask reads settled

        // ---- expand mask -> Xw bf16 tile [64 rows=(s,t)][256 f] ----
#pragma unroll
        for (int j = 0; j < 8; ++j) {
            const int c = tid + 256 * j;
            const int r = c >> 5, g = c & 31;          // row, 16B col-group (8 f)
            const int s = r >> 4, tt = t0 + (r & 15);
            const int ttc = (tt < T_REAL) ? tt : 0;    // clamp (stay in-bounds)
            uint32 m = mk[(size_t)(s * 100 + ttc) * 8 + (g >> 2)];
            m = (m >> ((g & 3) * 8)) & 0xFFu;
            if (tt >= T_REAL) m = 0;
            uint32 e0 = ((m & 1u)   ? 0x3F80u : 0u) | ((m & 2u)   ? 0x3F800000u : 0u);
            uint32 e1 = ((m & 4u)   ? 0x3F80u : 0u) | ((m & 8u)   ? 0x3F800000u : 0u);
            uint32 e2 = ((m & 16u)  ? 0x3F80u : 0u) | ((m & 32u)  ? 0x3F800000u : 0u);
            uint32 e3 = ((m & 64u)  ? 0x3F80u : 0u) | ((m & 128u) ? 0x3F800000u : 0u);
            *(uint4*)(xw + (size_t)r * 528 + g * 16) = make_uint4(e0, e1, e2, e3);
        }
        __syncthreads();

        // ---- L1 GEMM: [64 x 256] x [256 x 128], wave col-split (32 cols) ----
        {
            const int cb = wvu * 32;
            f32x4 acc[4][2];
            const float bia0 = wsF[B1F + cb + lr];
            const float bia1 = wsF[B1F + cb + 16 + lr];
#pragma unroll
            for (int rt = 0; rt < 4; ++rt) {
                acc[rt][0] = (f32x4){bia0, bia0, bia0, bia0};
                acc[rt][1] = (f32x4){bia1, bia1, bia1, bia1};
            }
#pragma unroll
            for (int ks = 0; ks < 8; ++ks) {
                const int koff = ks * 32 + lg * 8;
                const ushortT* wb0 = wsS + W1S + (cb + lr) * 256 + koff;
                const ushortT* wb1 = wb0 + 16 * 256;
                bf16x8 B00 = *(const bf16x8*)(wb0);
                bf16x8 B01 = *(const bf16x8*)(wb0 + 32768);
                bf16x8 B02 = *(const bf16x8*)(wb0 + 65536);
                bf16x8 B10 = *(const bf16x8*)(wb1);
                bf16x8 B11 = *(const bf16x8*)(wb1 + 32768);
                bf16x8 B12 = *(const bf16x8*)(wb1 + 65536);
#pragma unroll
                for (int rt = 0; rt < 4; ++rt) {
                    bf16x8 A = *(const bf16x8*)(xw + (size_t)(rt * 16 + lr) * 528 + koff * 2);
                    acc[rt][0] = MFMA(A, B00, acc[rt][0]);
                    acc[rt][1] = MFMA(A, B10, acc[rt][1]);
                    acc[rt][0] = MFMA(A, B01, acc[rt][0]);
                    acc[rt][1] = MFMA(A, B11, acc[rt][1]);
                    acc[rt][0] = MFMA(A, B02, acc[rt][0]);
                    acc[rt][1] = MFMA(A, B12, acc[rt][1]);
                }
            }
#pragma unroll
            for (int rt = 0; rt < 4; ++rt)
#pragma unroll
                for (int ct = 0; ct < 2; ++ct) {
                    float* up = u1 + (size_t)(rt * 128 + cb + ct * 16 + lr) * 17 + lg * 4;
#pragma unroll
                    for (int j = 0; j < 4; ++j) up[j] = acc[rt][ct][j];
                }
        }
        __syncthreads();

        // ---- LIF1: 512 neurons, 2/thread, pack spike bf16-pairs -> s1 ----
        {
            const float* uA = u1 + (size_t)(wvu * 128 + 2 * lane) * 17;
            const float* uB = uA + 17;
            char* dst = s1 + (size_t)(wvu * 16) * 272 + lane * 4;
            float vA = v1a, iA = i1a, vB = v1b, iB = i1b;
#pragma unroll
            for (int t = 0; t < 16; ++t) {
                float vdA = vA + 0.1f * ((0.0f - vA) + iA); bool zA = vdA > 1.0f;
                vA = zA ? 0.0f : vdA; iA = (iA - 0.2f * iA) + uA[t];
                float vdB = vB + 0.1f * ((0.0f - vB) + iB); bool zB = vdB > 1.0f;
                vB = zB ? 0.0f : vdB; iB = (iB - 0.2f * iB) + uB[t];
                *(uint32*)(dst + t * 272) = (zA ? 0x3F80u : 0u) | (zB ? 0x3F800000u : 0u);
            }
            v1a = vA; i1a = iA; v1b = vB; i1b = iB;
        }
        __syncthreads();

        // ---- L2 GEMM: [64 x 128] x [128 x 64], wave col-split (16 cols) ----
        {
            const int cb = wvu * 16;
            f32x4 acc[4];
            const float bia = wsF[B2F + cb + lr];
#pragma unroll
            for (int rt = 0; rt < 4; ++rt) acc[rt] = (f32x4){bia, bia, bia, bia};
#pragma unroll
            for (int ks = 0; ks < 4; ++ks) {
                const int koff = ks * 32 + lg * 8;
                const ushortT* wb = wsS + W2S + (cb + lr) * 128 + koff;
                bf16x8 Bh = *(const bf16x8*)(wb);
                bf16x8 Bm = *(const bf16x8*)(wb + 8192);
                bf16x8 Bl = *(const bf16x8*)(wb + 16384);
#pragma unroll
                for (int rt = 0; rt < 4; ++rt) {
                    bf16x8 A = *(const bf16x8*)(s1 + (size_t)(rt * 16 + lr) * 272 + koff * 2);
                    acc[rt] = MFMA(A, Bh, acc[rt]);
                    acc[rt] = MFMA(A, Bm, acc[rt]);
                    acc[rt] = MFMA(A, Bl, acc[rt]);
                }
            }
#pragma unroll
            for (int rt = 0; rt < 4; ++rt) {
                float* up = u2 + (size_t)(rt * 64 + cb + lr) * 17 + lg * 4;
#pragma unroll
                for (int j = 0; j < 4; ++j) up[j] = acc[rt][j];
            }
        }
        __syncthreads();

        // ---- LIF2: 256 neurons, lanes<32, all waves ----
        if (lane < 32) {
            const float* uA = u2 + (size_t)(wvu * 64 + 2 * lane) * 17;
            const float* uB = uA + 17;
            char* dst = s2 + (size_t)(wvu * 16) * 144 + lane * 4;
            float vA = v2a, iA = i2a, vB = v2b, iB = i2b;
#pragma unroll
            for (int t = 0; t < 16; ++t) {
                float vdA = vA + 0.1f * ((0.0f - vA) + iA); bool zA = vdA > 1.0f;
                vA = zA ? 0.0f : vdA; iA = (iA - 0.2f * iA) + uA[t];
                float vdB = vB + 0.1f * ((0.0f - vB) + iB); bool zB = vdB > 1.0f;
                vB = zB ? 0.0f : vdB; iB = (iB - 0.2f * iB) + uB[t];
                *(uint32*)(dst + t * 144) = (zA ? 0x3F80u : 0u) | (zB ? 0x3F800000u : 0u);
            }
            v2a = vA; i2a = iA; v2b = vB; i2b = iB;
        }
        __syncthreads();

        // ---- L3 GEMM: [64 x 64] x [64 x 32], waves 2x2 (rows x cols) ----
        {
            const int rhu = wvu >> 1, chu = wvu & 1;
            const int cb = chu * 16;
            f32x4 acc[2];
            const float bia = wsF[B3F + cb + lr];
            acc[0] = (f32x4){bia, bia, bia, bia};
            acc[1] = (f32x4){bia, bia, bia, bia};
#pragma unroll
            for (int ks = 0; ks < 2; ++ks) {
                const int koff = ks * 32 + lg * 8;
                const ushortT* wb = wsS + W3S + (cb + lr) * 64 + koff;
                bf16x8 Bh = *(const bf16x8*)(wb);
                bf16x8 Bm = *(const bf16x8*)(wb + 2048);
                bf16x8 Bl = *(const bf16x8*)(wb + 4096);
#pragma unroll
                for (int r = 0; r < 2; ++r) {
                    bf16x8 A = *(const bf16x8*)(s2 + (size_t)((rhu * 2 + r) * 16 + lr) * 144 + koff * 2);
                    acc[r] = MFMA(A, Bh, acc[r]);
                    acc[r] = MFMA(A, Bm, acc[r]);
                    acc[r] = MFMA(A, Bl, acc[r]);
                }
            }
#pragma unroll
            for (int r = 0; r < 2; ++r) {
                float* up = u3 + (size_t)((rhu * 2 + r) * 32 + cb + lr) * 17 + lg * 4;
#pragma unroll
                for (int j = 0; j < 4; ++j) up[j] = acc[r][j];
            }
        }
        __syncthreads();

        // ---- LIF3: 128 neurons, lanes<16, all waves ----
        if (lane < 16) {
            const float* uA = u3 + (size_t)(wvu * 32 + 2 * lane) * 17;
            const float* uB = uA + 17;
            char* dst = s3 + (size_t)(wvu * 16) * 80 + lane * 4;
            float vA = v3a, iA = i3a, vB = v3b, iB = i3b;
#pragma unroll
            for (int t = 0; t < 16; ++t) {
                float vdA = vA + 0.1f * ((0.0f - vA) + iA); bool zA = vdA > 1.0f;
                vA = zA ? 0.0f : vdA; iA = (iA - 0.2f * iA) + uA[t];
                float vdB = vB + 0.1f * ((0.0f - vB) + iB); bool zB = vdB > 1.0f;
                vB = zB ? 0.0f : vdB; iB = (iB - 0.2f * iB) + uB[t];
                *(uint32*)(dst + t * 80) = (zA ? 0x3F80u : 0u) | (zB ? 0x3F800000u : 0u);
            }
            v3a = vA; i3a = iA; v3b = vB; i3b = iB;
        }
        __syncthreads();

        // ---- Lout GEMM: [64 x 32] x [32 x 16(2 real)], wave row-split ----
        {
            const float bia = (lr < 2) ? wsF[BOF + lr] : 0.f;
            f32x4 acc = (f32x4){bia, bia, bia, bia};
            const int koff = lg * 8;
            const ushortT* wb = wsS + WOS + lr * 32 + koff;
            bf16x8 Bh = *(const bf16x8*)(wb);
            bf16x8 Bm = *(const bf16x8*)(wb + 512);
            bf16x8 Bl = *(const bf16x8*)(wb + 1024);
            bf16x8 A = *(const bf16x8*)(s3 + (size_t)(wvu * 16 + lr) * 80 + koff * 2);
            acc = MFMA(A, Bh, acc);
            acc = MFMA(A, Bm, acc);
            acc = MFMA(A, Bl, acc);
            if (lr < 2) {
                float* up = uo + (size_t)(wvu * 2 + lr) * 17 + lg * 4;
#pragma unroll
                for (int j = 0; j < 4; ++j) up[j] = acc[j];
            }
        }
        __syncthreads();

        // ---- LIF out + accumulate (t<100 guard) ----
        if (tid < 8) {
            const float* ur = uo + tid * 17;
            float v = vo, ii = io, a = aspk;
#pragma unroll
            for (int t = 0; t < 16; ++t) {
                float vd = v + 0.1f * ((0.0f - v) + ii);
                bool z = vd > 1.0f; v = z ? 0.0f : vd;
                ii = (ii - 0.2f * ii) + ur[t];
                if (t0 + t < T_REAL) a += z ? 1.0f : 0.0f;
            }
            vo = v; io = ii; aspk = a;
        }
    }

    if (tid < 8) out[(size_t)(b0 + (tid >> 1)) * 2 + (tid & 1)] = aspk;
}

extern "C" void kernel_launch(void* const* d_in, const int* in_sizes, int n_in,
                              void* d_out, int out_size, void* d_ws, size_t ws_size,
                              hipStream_t stream)
{
    const float* x    = (const float*)d_in[0];
    const float* bn0g = (const float*)d_in[1];
    const float* bn0b = (const float*)d_in[2];
    const float* bn0m = (const float*)d_in[3];
    const float* bn0v = (const float*)d_in[4];
    const float* W1   = (const float*)d_in[5];
    const float* b1   = (const float*)d_in[6];
    const float* bn1g = (const float*)d_in[7];
    const float* bn1b = (const float*)d_in[8];
    const float* bn1m = (const float*)d_in[9];
    const float* bn1v = (const float*)d_in[10];
    const float* W2   = (const float*)d_in[11];
    const float* b2   = (const float*)d_in[12];
    const float* bn2g = (const float*)d_in[13];
    const float* bn2b = (const float*)d_in[14];
    const float* bn2m = (const float*)d_in[15];
    const float* bn2v = (const float*)d_in[16];
    const float* W3   = (const float*)d_in[17];
    const float* b3   = (const float*)d_in[18];
    const float* bn3g = (const float*)d_in[19];
    const float* bn3b = (const float*)d_in[20];
    const float* bn3m = (const float*)d_in[21];
    const float* bn3v = (const float*)d_in[22];
    const float* Wo   = (const float*)d_in[23];
    const float* bo   = (const float*)d_in[24];

    ushortT* wsS = (ushortT*)d_ws;
    float*   wsF = (float*)d_ws;
    float*   pout = (float*)d_out;

    prep_w<<<170, 256, 0, stream>>>(W1, W2, W3, Wo, bn0g, bn0v, bn1g, bn1v,
                                    bn2g, bn2v, bn3g, bn3v, wsS);
    prep_bias<<<1, 256, 0, stream>>>(bn0g, bn0b, bn0m, bn0v, b1, W1,
                                     bn1g, bn1b, bn1m, bn1v,
                                     b2, bn2g, bn2b, bn2m, bn2v,
                                     b3, bn3g, bn3b, bn3m, bn3v, bo, wsF);
    snn_main<<<1024, 256, 0, stream>>>(x, wsS, wsF, pout);
}

// Round 8
// 1001.389 us; speedup vs baseline: 2.8253x; 1.0343x over previous
//
#include <hip/hip_runtime.h>
#include <stdint.h>

typedef unsigned int   uint32;
typedef unsigned short ushortT;
typedef short bf16x8 __attribute__((ext_vector_type(8)));
typedef float f32x4  __attribute__((ext_vector_type(4)));

#define T_REAL 100

// ---- workspace layout ----
// short (bf16-bit) region:
#define W1S 0          // 3 x [128][256]
#define W2S 98304      // 3 x [64][128]
#define W3S 122880     // 3 x [32][64]
#define WOS 129024     // 3 x [16][32] (rows 2..15 zero)
// float region (dword offsets into ws):
#define B1F 65280
#define B2F 65408
#define B3F 65472
#define BOF 65504

// ---- LDS layout (bytes) — aggressive aliasing, peak 47616 -> 3 blocks/CU ----
// [0,34816): Xw [64][264]bf16 (33792) -> u1 [512][17]f32 (34816) -> s1 [64][272B]
//            (17408, over dead u1) -> s2 [64][144B] (9216) -> s3 [64][80B] (5120)
// [17408,34816): u2 [256][17]f32 (over dead Xw/u1 upper half)
// [9216,17920):  u3 [128][17]f32 (over dead s1 tail region)
// [9216,9760):   uo [8][17]f32  (over dead u3)
// [34816,47616): spike bitmask [4][100][8]u32 (persistent)
#define U2_B 17408
#define U3_B 9216
#define S2_B 0
#define S3_B 0
#define UO_B 9216
#define MK_BASE 34816
#define LDS_BYTES 47616

#define MFMA(a,b,c) __builtin_amdgcn_mfma_f32_16x16x32_bf16(a,b,c,0,0,0)

__device__ __forceinline__ ushortT bf16rne(float x) {
    uint32 u = __float_as_uint(x);
    return (ushortT)((u + 0x7FFFu + ((u >> 16) & 1u)) >> 16);
}

// exact 3-way split: w == hi + mid + lo in fp32
__device__ __forceinline__ void split3(float w, ushortT& a, ushortT& b, ushortT& c) {
    a = bf16rne(w); float fa = __uint_as_float((uint32)a << 16);
    float r1 = w - fa;
    b = bf16rne(r1); float fb = __uint_as_float((uint32)b << 16);
    float r2 = r1 - fb;
    c = bf16rne(r2);
}

__global__ void prep_w(const float* __restrict__ W1, const float* __restrict__ W2,
                       const float* __restrict__ W3, const float* __restrict__ Wo,
                       const float* __restrict__ bn0g, const float* __restrict__ bn0v,
                       const float* __restrict__ bn1g, const float* __restrict__ bn1v,
                       const float* __restrict__ bn2g, const float* __restrict__ bn2v,
                       const float* __restrict__ bn3g, const float* __restrict__ bn3v,
                       ushortT* __restrict__ wsS)
{
    int idx = blockIdx.x * 256 + threadIdx.x;
    float w; int base, size, off;
    if (idx < 32768) {                 // W1 [128][256] * A[f] * G1[h]
        int h = idx >> 8, f = idx & 255;
        float A = bn0g[f] / sqrtf(bn0v[f] + 1e-5f);
        float G = bn1g[h] / sqrtf(bn1v[h] + 1e-5f);
        w = W1[idx] * A * G; base = W1S; size = 32768; off = idx;
    } else if (idx < 40960) {          // W2 [64][128] * G2[h]
        int r = idx - 32768; int h = r >> 7;
        float G = bn2g[h] / sqrtf(bn2v[h] + 1e-5f);
        w = W2[r] * G; base = W2S; size = 8192; off = r;
    } else if (idx < 43008) {          // W3 [32][64] * G3[h]
        int r = idx - 40960; int h = r >> 6;
        float G = bn3g[h] / sqrtf(bn3v[h] + 1e-5f);
        w = W3[r] * G; base = W3S; size = 2048; off = r;
    } else if (idx < 43520) {          // Wo padded [16][32]
        int r = idx - 43008; int o = r >> 5, k = r & 31;
        w = (o < 2) ? Wo[o * 32 + k] : 0.f;
        base = WOS; size = 512; off = r;
    } else return;
    ushortT a, b, c; split3(w, a, b, c);
    wsS[base + off] = a; wsS[base + size + off] = b; wsS[base + 2 * size + off] = c;
}

__global__ void prep_bias(const float* __restrict__ bn0g, const float* __restrict__ bn0b,
                          const float* __restrict__ bn0m, const float* __restrict__ bn0v,
                          const float* __restrict__ b1,   const float* __restrict__ W1,
                          const float* __restrict__ bn1g, const float* __restrict__ bn1b,
                          const float* __restrict__ bn1m, const float* __restrict__ bn1v,
                          const float* __restrict__ b2,   const float* __restrict__ bn2g,
                          const float* __restrict__ bn2b, const float* __restrict__ bn2m,
                          const float* __restrict__ bn2v,
                          const float* __restrict__ b3,   const float* __restrict__ bn3g,
                          const float* __restrict__ bn3b, const float* __restrict__ bn3m,
                          const float* __restrict__ bn3v,
                          const float* __restrict__ bo,   float* __restrict__ wsF)
{
    __shared__ float Cs[256];
    const int tid = threadIdx.x;
    {
        float A = bn0g[tid] / sqrtf(bn0v[tid] + 1e-5f);
        Cs[tid] = bn0b[tid] - bn0m[tid] * A;   // BN0 applied to x=0
    }
    __syncthreads();
    if (tid < 128) {
        float G  = bn1g[tid] / sqrtf(bn1v[tid] + 1e-5f);
        float Bn = bn1b[tid] - bn1m[tid] * G;
        float s  = b1[tid];
        const float* wr = W1 + tid * 256;
        for (int f = 0; f < 256; ++f) s = fmaf(wr[f], Cs[f], s);
        wsF[B1F + tid] = G * s + Bn;
    }
    if (tid < 64) {
        float G = bn2g[tid] / sqrtf(bn2v[tid] + 1e-5f);
        wsF[B2F + tid] = G * b2[tid] + (bn2b[tid] - bn2m[tid] * G);
    }
    if (tid < 32) {
        float G = bn3g[tid] / sqrtf(bn3v[tid] + 1e-5f);
        wsF[B3F + tid] = G * b3[tid] + (bn3b[tid] - bn3m[tid] * G);
    }
    if (tid < 2) wsF[BOF + tid] = bo[tid];
}

__global__ __launch_bounds__(256, 3) void snn_main(
    const float* __restrict__ xin,
    const ushortT* __restrict__ wsS,
    const float* __restrict__ wsF,
    float* __restrict__ out)
{
    __shared__ uint4 ldsq[LDS_BYTES / 16];
    char* lds = (char*)ldsq;
    char* xw = lds;                       // [64][264] bf16, row stride 528 B
    float* u1 = (float*)lds;              // [512][17] f32 (over Xw, sequenced)
    char* s1 = lds;                       // [64][272B] (over dead u1, after mid-sync)
    float* u2 = (float*)(lds + U2_B);     // [256][17] f32
    char* s2 = lds + S2_B;                // [64][144B]
    float* u3 = (float*)(lds + U3_B);     // [128][17] f32
    char* s3 = lds + S3_B;                // [64][80B]
    float* uo = (float*)(lds + UO_B);     // [8][17] f32
    uint32* mk = (uint32*)(lds + MK_BASE);// [4][100][8] spike bits

    const int tid  = threadIdx.x;
    const int lane = tid & 63;
    const int wv   = tid >> 6;
    const int wvu  = __builtin_amdgcn_readfirstlane(wv);
    const int lr   = lane & 15;    // MFMA in-tile row/col
    const int lg   = lane >> 4;    // MFMA k-group / t-group
    const int b0   = blockIdx.x * 4;

    // ---- stage spike bitmask once: wave = feature-group, lane = feature ----
    {
        const int fg = wvu;                      // features fg*64 .. fg*64+63
        for (int s = 0; s < 4; ++s) {
            const float* rp = xin + ((size_t)(b0 + s) * 256 + fg * 64 + lane) * T_REAL;
            uint32* mrow = mk + (size_t)(s * 100) * 8 + fg * 2 + (lane >> 5);
#pragma unroll 1
            for (int q = 0; q < 25; ++q) {
                float4 v = *(const float4*)(rp + q * 4);
                unsigned long long bx = __ballot(v.x > 0.5f);
                unsigned long long by = __ballot(v.y > 0.5f);
                unsigned long long bz = __ballot(v.z > 0.5f);
                unsigned long long bw = __ballot(v.w > 0.5f);
                if ((lane & 31) == 0) {
                    const int sh = (lane >> 5) * 32;
                    mrow[(q * 4 + 0) * 8] = (uint32)(bx >> sh);
                    mrow[(q * 4 + 1) * 8] = (uint32)(by >> sh);
                    mrow[(q * 4 + 2) * 8] = (uint32)(bz >> sh);
                    mrow[(q * 4 + 3) * 8] = (uint32)(bw >> sh);
                }
            }
        }
    }

    // persistent LIF states
    float v1a = 0, i1a = 0, v1b = 0, i1b = 0; // L1: (s=wv, h=2*lane, 2*lane+1)
    float v2a = 0, i2a = 0, v2b = 0, i2b = 0; // L2: lane<32, (s=wv, h=2*lane,+1)
    float v3a = 0, i3a = 0, v3b = 0, i3b = 0; // L3: lane<16
    float vo = 0, io = 0, aspk = 0;           // out: tid<8 -> (s=tid>>1, o=tid&1)

#pragma unroll 1
    for (int w = 0; w < 7; ++w) {
        const int t0 = w * 16;
        __syncthreads();     // staging done (w=0) / prev-window region reads settled

        // ---- expand mask -> Xw bf16 tile [64 rows=(s,t)][256 f] ----
#pragma unroll
        for (int j = 0; j < 8; ++j) {
            const int c = tid + 256 * j;
            const int r = c >> 5, g = c & 31;          // row, 16B col-group (8 f)
            const int s = r >> 4, tt = t0 + (r & 15);
            const int ttc = (tt < T_REAL) ? tt : 0;    // clamp (stay in-bounds)
            uint32 m = mk[(size_t)(s * 100 + ttc) * 8 + (g >> 2)];
            m = (m >> ((g & 3) * 8)) & 0xFFu;
            if (tt >= T_REAL) m = 0;
            uint32 e0 = ((m & 1u)   ? 0x3F80u : 0u) | ((m & 2u)   ? 0x3F800000u : 0u);
            uint32 e1 = ((m & 4u)   ? 0x3F80u : 0u) | ((m & 8u)   ? 0x3F800000u : 0u);
            uint32 e2 = ((m & 16u)  ? 0x3F80u : 0u) | ((m & 32u)  ? 0x3F800000u : 0u);
            uint32 e3 = ((m & 64u)  ? 0x3F80u : 0u) | ((m & 128u) ? 0x3F800000u : 0u);
            *(uint4*)(xw + (size_t)r * 528 + g * 16) = make_uint4(e0, e1, e2, e3);
        }
        __syncthreads();

        // ---- L1 GEMM: [64 x 256] x [256 x 128], wave col-split (32 cols) ----
        {
            const int cb = wvu * 32;
            f32x4 acc[4][2];
            const float bia0 = wsF[B1F + cb + lr];
            const float bia1 = wsF[B1F + cb + 16 + lr];
#pragma unroll
            for (int rt = 0; rt < 4; ++rt) {
                acc[rt][0] = (f32x4){bia0, bia0, bia0, bia0};
                acc[rt][1] = (f32x4){bia1, bia1, bia1, bia1};
            }
#pragma unroll 2
            for (int ks = 0; ks < 8; ++ks) {
                const int koff = ks * 32 + lg * 8;
                const ushortT* wb0 = wsS + W1S + (cb + lr) * 256 + koff;
                const ushortT* wb1 = wb0 + 16 * 256;
                bf16x8 B00 = *(const bf16x8*)(wb0);
                bf16x8 B01 = *(const bf16x8*)(wb0 + 32768);
                bf16x8 B02 = *(const bf16x8*)(wb0 + 65536);
                bf16x8 B10 = *(const bf16x8*)(wb1);
                bf16x8 B11 = *(const bf16x8*)(wb1 + 32768);
                bf16x8 B12 = *(const bf16x8*)(wb1 + 65536);
#pragma unroll
                for (int rt = 0; rt < 4; ++rt) {
                    bf16x8 A = *(const bf16x8*)(xw + (size_t)(rt * 16 + lr) * 528 + koff * 2);
                    acc[rt][0] = MFMA(A, B00, acc[rt][0]);
                    acc[rt][1] = MFMA(A, B10, acc[rt][1]);
                    acc[rt][0] = MFMA(A, B01, acc[rt][0]);
                    acc[rt][1] = MFMA(A, B11, acc[rt][1]);
                    acc[rt][0] = MFMA(A, B02, acc[rt][0]);
                    acc[rt][1] = MFMA(A, B12, acc[rt][1]);
                }
            }
            __syncthreads();   // all waves done reading Xw; u1 may overwrite it
#pragma unroll
            for (int rt = 0; rt < 4; ++rt)
#pragma unroll
                for (int ct = 0; ct < 2; ++ct) {
                    float* up = u1 + (size_t)(rt * 128 + cb + ct * 16 + lr) * 17 + lg * 4;
#pragma unroll
                    for (int j = 0; j < 4; ++j) up[j] = acc[rt][ct][j];
                }
        }
        __syncthreads();       // u1 ready

        // ---- LIF1: 512 neurons, 2/thread; read u to regs, sync, write s1 ----
        {
            const float* uA = u1 + (size_t)(wvu * 128 + 2 * lane) * 17;
            const float* uB = uA + 17;
            float ua[16], ub[16];
#pragma unroll
            for (int t = 0; t < 16; ++t) { ua[t] = uA[t]; ub[t] = uB[t]; }
            __syncthreads();   // all u1 reads done; s1 may overwrite u1 region
            char* dst = s1 + (size_t)(wvu * 16) * 272 + lane * 4;
            float vA = v1a, iA = i1a, vB = v1b, iB = i1b;
#pragma unroll
            for (int t = 0; t < 16; ++t) {
                float vdA = vA + 0.1f * ((0.0f - vA) + iA); bool zA = vdA > 1.0f;
                vA = zA ? 0.0f : vdA; iA = (iA - 0.2f * iA) + ua[t];
                float vdB = vB + 0.1f * ((0.0f - vB) + iB); bool zB = vdB > 1.0f;
                vB = zB ? 0.0f : vdB; iB = (iB - 0.2f * iB) + ub[t];
                *(uint32*)(dst + t * 272) = (zA ? 0x3F80u : 0u) | (zB ? 0x3F800000u : 0u);
            }
            v1a = vA; i1a = iA; v1b = vB; i1b = iB;
        }
        __syncthreads();       // s1 ready

        // ---- L2 GEMM: [64 x 128] x [128 x 64]; writes u2 (disjoint from s1) ----
        {
            const int cb = wvu * 16;
            f32x4 acc[4];
            const float bia = wsF[B2F + cb + lr];
#pragma unroll
            for (int rt = 0; rt < 4; ++rt) acc[rt] = (f32x4){bia, bia, bia, bia};
#pragma unroll 2
            for (int ks = 0; ks < 4; ++ks) {
                const int koff = ks * 32 + lg * 8;
                const ushortT* wb = wsS + W2S + (cb + lr) * 128 + koff;
                bf16x8 Bh = *(const bf16x8*)(wb);
                bf16x8 Bm = *(const bf16x8*)(wb + 8192);
                bf16x8 Bl = *(const bf16x8*)(wb + 16384);
#pragma unroll
                for (int rt = 0; rt < 4; ++rt) {
                    bf16x8 A = *(const bf16x8*)(s1 + (size_t)(rt * 16 + lr) * 272 + koff * 2);
                    acc[rt] = MFMA(A, Bh, acc[rt]);
                    acc[rt] = MFMA(A, Bm, acc[rt]);
                    acc[rt] = MFMA(A, Bl, acc[rt]);
                }
            }
#pragma unroll
            for (int rt = 0; rt < 4; ++rt) {
                float* up = u2 + (size_t)(rt * 64 + cb + lr) * 17 + lg * 4;
#pragma unroll
                for (int j = 0; j < 4; ++j) up[j] = acc[rt][j];
            }
        }
        __syncthreads();       // u2 ready; s1 dead

        // ---- LIF2: 256 neurons, lanes<32; reads u2, writes s2 (disjoint) ----
        if (lane < 32) {
            const float* uA = u2 + (size_t)(wvu * 64 + 2 * lane) * 17;
            const float* uB = uA + 17;
            char* dst = s2 + (size_t)(wvu * 16) * 144 + lane * 4;
            float vA = v2a, iA = i2a, vB = v2b, iB = i2b;
#pragma unroll
            for (int t = 0; t < 16; ++t) {
                float vdA = vA + 0.1f * ((0.0f - vA) + iA); bool zA = vdA > 1.0f;
                vA = zA ? 0.0f : vdA; iA = (iA - 0.2f * iA) + uA[t];
                float vdB = vB + 0.1f * ((0.0f - vB) + iB); bool zB = vdB > 1.0f;
                vB = zB ? 0.0f : vdB; iB = (iB - 0.2f * iB) + uB[t];
                *(uint32*)(dst + t * 144) = (zA ? 0x3F80u : 0u) | (zB ? 0x3F800000u : 0u);
            }
            v2a = vA; i2a = iA; v2b = vB; i2b = iB;
        }
        __syncthreads();       // s2 ready; u2 dead

        // ---- L3 GEMM: [64 x 64] x [64 x 32]; writes u3 (disjoint from s2) ----
        {
            const int rhu = wvu >> 1, chu = wvu & 1;
            const int cb = chu * 16;
            f32x4 acc[2];
            const float bia = wsF[B3F + cb + lr];
            acc[0] = (f32x4){bia, bia, bia, bia};
            acc[1] = (f32x4){bia, bia, bia, bia};
#pragma unroll
            for (int ks = 0; ks < 2; ++ks) {
                const int koff = ks * 32 + lg * 8;
                const ushortT* wb = wsS + W3S + (cb + lr) * 64 + koff;
                bf16x8 Bh = *(const bf16x8*)(wb);
                bf16x8 Bm = *(const bf16x8*)(wb + 2048);
                bf16x8 Bl = *(const bf16x8*)(wb + 4096);
#pragma unroll
                for (int r = 0; r < 2; ++r) {
                    bf16x8 A = *(const bf16x8*)(s2 + (size_t)((rhu * 2 + r) * 16 + lr) * 144 + koff * 2);
                    acc[r] = MFMA(A, Bh, acc[r]);
                    acc[r] = MFMA(A, Bm, acc[r]);
                    acc[r] = MFMA(A, Bl, acc[r]);
                }
            }
#pragma unroll
            for (int r = 0; r < 2; ++r) {
                float* up = u3 + (size_t)((rhu * 2 + r) * 32 + cb + lr) * 17 + lg * 4;
#pragma unroll
                for (int j = 0; j < 4; ++j) up[j] = acc[r][j];
            }
        }
        __syncthreads();       // u3 ready; s2 dead

        // ---- LIF3: 128 neurons, lanes<16; reads u3, writes s3 (disjoint) ----
        if (lane < 16) {
            const float* uA = u3 + (size_t)(wvu * 32 + 2 * lane) * 17;
            const float* uB = uA + 17;
            char* dst = s3 + (size_t)(wvu * 16) * 80 + lane * 4;
            float vA = v3a, iA = i3a, vB = v3b, iB = i3b;
#pragma unroll
            for (int t = 0; t < 16; ++t) {
                float vdA = vA + 0.1f * ((0.0f - vA) + iA); bool zA = vdA > 1.0f;
                vA = zA ? 0.0f : vdA; iA = (iA - 0.2f * iA) + uA[t];
                float vdB = vB + 0.1f * ((0.0f - vB) + iB); bool zB = vdB > 1.0f;
                vB = zB ? 0.0f : vdB; iB = (iB - 0.2f * iB) + uB[t];
                *(uint32*)(dst + t * 80) = (zA ? 0x3F80u : 0u) | (zB ? 0x3F800000u : 0u);
            }
            v3a = vA; i3a = iA; v3b = vB; i3b = iB;
        }
        __syncthreads();       // s3 ready; u3 dead

        // ---- Lout GEMM: [64 x 32] x [32 x 16(2 real)]; writes uo (over dead u3) ----
        {
            const float bia = (lr < 2) ? wsF[BOF + lr] : 0.f;
            f32x4 acc = (f32x4){bia, bia, bia, bia};
            const int koff = lg * 8;
            const ushortT* wb = wsS + WOS + lr * 32 + koff;
            bf16x8 Bh = *(const bf16x8*)(wb);
            bf16x8 Bm = *(const bf16x8*)(wb + 512);
            bf16x8 Bl = *(const bf16x8*)(wb + 1024);
            bf16x8 A = *(const bf16x8*)(s3 + (size_t)(wvu * 16 + lr) * 80 + koff * 2);
            acc = MFMA(A, Bh, acc);
            acc = MFMA(A, Bm, acc);
            acc = MFMA(A, Bl, acc);
            if (lr < 2) {
                float* up = uo + (size_t)(wvu * 2 + lr) * 17 + lg * 4;
#pragma unroll
                for (int j = 0; j < 4; ++j) up[j] = acc[j];
            }
        }
        __syncthreads();       // uo ready

        // ---- LIF out + accumulate (t<100 guard) ----
        if (tid < 8) {
            const float* ur = uo + tid * 17;
            float v = vo, ii = io, a = aspk;
#pragma unroll
            for (int t = 0; t < 16; ++t) {
                float vd = v + 0.1f * ((0.0f - v) + ii);
                bool z = vd > 1.0f; v = z ? 0.0f : vd;
                ii = (ii - 0.2f * ii) + ur[t];
                if (t0 + t < T_REAL) a += z ? 1.0f : 0.0f;
            }
            vo = v; io = ii; aspk = a;
        }
    }

    if (tid < 8) out[(size_t)(b0 + (tid >> 1)) * 2 + (tid & 1)] = aspk;
}

extern "C" void kernel_launch(void* const* d_in, const int* in_sizes, int n_in,
                              void* d_out, int out_size, void* d_ws, size_t ws_size,
                              hipStream_t stream)
{
    const float* x    = (const float*)d_in[0];
    const float* bn0g = (const float*)d_in[1];
    const float* bn0b = (const float*)d_in[2];
    const float* bn0m = (const float*)d_in[3];
    const float* bn0v = (const float*)d_in[4];
    const float* W1   = (const float*)d_in[5];
    const float* b1   = (const float*)d_in[6];
    const float* bn1g = (const float*)d_in[7];
    const float* bn1b = (const float*)d_in[8];
    const float* bn1m = (const float*)d_in[9];
    const float* bn1v = (const float*)d_in[10];
    const float* W2   = (const float*)d_in[11];
    const float* b2   = (const float*)d_in[12];
    const float* bn2g = (const float*)d_in[13];
    const float* bn2b = (const float*)d_in[14];
    const float* bn2m = (const float*)d_in[15];
    const float* bn2v = (const float*)d_in[16];
    const float* W3   = (const float*)d_in[17];
    const float* b3   = (const float*)d_in[18];
    const float* bn3g = (const float*)d_in[19];
    const float* bn3b = (const float*)d_in[20];
    const float* bn3m = (const float*)d_in[21];
    const float* bn3v = (const float*)d_in[22];
    const float* Wo   = (const float*)d_in[23];
    const float* bo   = (const float*)d_in[24];

    ushortT* wsS = (ushortT*)d_ws;
    float*   wsF = (float*)d_ws;
    float*   pout = (float*)d_out;

    prep_w<<<170, 256, 0, stream>>>(W1, W2, W3, Wo, bn0g, bn0v, bn1g, bn1v,
                                    bn2g, bn2v, bn3g, bn3v, wsS);
    prep_bias<<<1, 256, 0, stream>>>(bn0g, bn0b, bn0m, bn0v, b1, W1,
                                     bn1g, bn1b, bn1m, bn1v,
                                     b2, bn2g, bn2b, bn2m, bn2v,
                                     b3, bn3g, bn3b, bn3m, bn3v, bo, wsF);
    snn_main<<<1024, 256, 0, stream>>>(x, wsS, wsF, pout);
}